// Round 2
// 389.967 us; speedup vs baseline: 1.0408x; 1.0408x over previous
//
#include <hip/hip_runtime.h>
#include <math.h>

// x: (16, 52, 256, 256) fp32, GROUPS=52, cpg=1. Each (b,g) slice of 65536
// elements is independent: argmax+mean -> sim stats -> gated output.
// One 1024-thread block per slice; the whole 256 KB slice lives in
// registers (16 float4/thread). __launch_bounds__(1024,4) caps occupancy at
// exactly one block/CU -> 128-VGPR budget -> no scratch spill (the previous
// build spilled: VGPR_Count=64 with a 64-reg payload, WRITE_SIZE 1.31x output).
// The separable Gaussian dist is precomputed into 256-entry row/col LDS
// tables after the argmax is known, so sweeps 2/3 are pure FMA + sigmoid.
#define Gn 52
#define Hn 256
#define Wn 256
#define HW (Hn * Wn)     // 65536
#define HW4 (HW / 4)     // 16384
#define BG 832
#define TPB 1024
#define VPT 16           // float4 per thread; TPB*VPT == HW4

typedef float vf4 __attribute__((ext_vector_type(4)));  // for nontemporal store

__global__ __launch_bounds__(TPB, 4) void k_fused(
    const float4* __restrict__ x4,
    const float* __restrict__ weight, const float* __restrict__ bias,
    const float* __restrict__ one_,  const float* __restrict__ zero,
    const float* __restrict__ theta, const float* __restrict__ scale,
    float4* __restrict__ out4)
{
    const int bg   = blockIdx.x;
    const int g    = bg % Gn;
    const int t    = threadIdx.x;
    const int wave = t >> 6;
    const int lane = t & 63;
    const size_t base4 = (size_t)bg * HW4;
    const float4* xp = x4 + base4;

    __shared__ float rv[16];
    __shared__ int   ri[16];
    __shared__ float r1[16];
    __shared__ float r2[16];
    __shared__ float bc[6];
    __shared__ float wcol[256];   // 0.5*A*gc(c)
    __shared__ float urow[256];   // 0.5*A*gr(r) + B

    // ---- load entire slice into registers (coalesced, 16 outstanding) ----
    float4 v[VPT];
    #pragma unroll
    for (int k = 0; k < VPT; ++k) v[k] = xp[t + k * TPB];

    // ---- sweep 1: argmax (first occurrence) + sum, 2-way ILP ----
    // element index e = (t + k*TPB)*4: row r = wave + 16k, col c = 4*lane + j
    float vmaxA = -INFINITY, vmaxB = -INFINITY;
    int   imaxA = 0x7fffffff, imaxB = 0x7fffffff;
    float sumA = 0.f, sumB = 0.f;
    #pragma unroll
    for (int k = 0; k < VPT; k += 2) {
        int e0 = (t + k * TPB) * 4;
        float4 q0 = v[k];
        sumA += (q0.x + q0.y) + (q0.z + q0.w);
        if (q0.x > vmaxA) { vmaxA = q0.x; imaxA = e0; }
        if (q0.y > vmaxA) { vmaxA = q0.y; imaxA = e0 + 1; }
        if (q0.z > vmaxA) { vmaxA = q0.z; imaxA = e0 + 2; }
        if (q0.w > vmaxA) { vmaxA = q0.w; imaxA = e0 + 3; }
        int e1 = (t + (k + 1) * TPB) * 4;
        float4 q1 = v[k + 1];
        sumB += (q1.x + q1.y) + (q1.z + q1.w);
        if (q1.x > vmaxB) { vmaxB = q1.x; imaxB = e1; }
        if (q1.y > vmaxB) { vmaxB = q1.y; imaxB = e1 + 1; }
        if (q1.z > vmaxB) { vmaxB = q1.z; imaxB = e1 + 2; }
        if (q1.w > vmaxB) { vmaxB = q1.w; imaxB = e1 + 3; }
    }
    float sum = sumA + sumB;
    float vmax = vmaxA; int imax = imaxA;
    if (vmaxB > vmax || (vmaxB == vmax && imaxB < imax)) { vmax = vmaxB; imax = imaxB; }
    #pragma unroll
    for (int off = 32; off > 0; off >>= 1) {
        float ov = __shfl_down(vmax, off);
        int   oi = __shfl_down(imax, off);
        float os = __shfl_down(sum,  off);
        sum += os;
        // larger wins; tie -> smaller index (numpy first occurrence)
        if (ov > vmax || (ov == vmax && oi < imax)) { vmax = ov; imax = oi; }
    }
    if (lane == 0) { rv[wave] = vmax; ri[wave] = imax; r1[wave] = sum; }
    __syncthreads();
    if (t < 64) {   // wave 0: parallel cross-wave reduce of 16 partials
        float bv = (t < 16) ? rv[t] : -INFINITY;
        int   bi = (t < 16) ? ri[t] : 0x7fffffff;
        float bs = (t < 16) ? r1[t] : 0.f;
        #pragma unroll
        for (int off = 8; off > 0; off >>= 1) {
            float ov = __shfl_down(bv, off);
            int   oi = __shfl_down(bi, off);
            float os = __shfl_down(bs, off);
            bs += os;
            if (ov > bv || (ov == bv && oi < bi)) { bv = ov; bi = oi; }
        }
        if (t == 0) {
            bc[0] = bv;                        // qval
            bc[1] = (float)(bi >> 8);          // qrow
            bc[2] = (float)(bi & 255);         // qcol
            bc[3] = bs * (1.f / (float)HW);    // gap
        }
    }
    __syncthreads();

    // ---- build separable Gaussian tables: 512 exps/block instead of 160K ----
    // sim = (A*0.5*(gr+gc) + B)*x = (urow[r] + wcol[c]) * x
    const float sigma   = scale[0];
    const float inv2s2  = 0.5f / (sigma * sigma);
    const float lognorm = -logf(sigma) - 0.9189385332046727f; // -0.5*log(2pi)
    const float A   = zero[g] * bc[0];
    const float Bc  = one_[g] * bc[3];
    const float A05 = 0.5f * A;
    if (t < 256) {
        float zc = ((float)t - bc[2]) * theta[1];
        wcol[t] = A05 * __expf(lognorm - zc * zc * inv2s2);
    } else if (t < 512) {
        float zr = ((float)(t - 256) - bc[1]) * theta[0];
        urow[t - 256] = A05 * __expf(lognorm - zr * zr * inv2s2) + Bc;
    }
    __syncthreads();

    // per-thread columns are k-invariant: one b128 LDS read, kept in regs
    const float4 cw = *reinterpret_cast<const float4*>(&wcol[(t & 63) << 2]);

    // ---- sweep 2: sim statistics (pure FMA; row coeff is a broadcast read) ----
    float s1 = 0.f, s2 = 0.f;
    #pragma unroll
    for (int k = 0; k < VPT; ++k) {
        const float ur = urow[wave + 16 * k];
        float4 q = v[k];
        float f, sim;
        f = ur + cw.x; sim = f * q.x; s1 += sim; s2 = fmaf(sim, sim, s2);
        f = ur + cw.y; sim = f * q.y; s1 += sim; s2 = fmaf(sim, sim, s2);
        f = ur + cw.z; sim = f * q.z; s1 += sim; s2 = fmaf(sim, sim, s2);
        f = ur + cw.w; sim = f * q.w; s1 += sim; s2 = fmaf(sim, sim, s2);
    }
    #pragma unroll
    for (int off = 32; off > 0; off >>= 1) {
        s1 += __shfl_down(s1, off);
        s2 += __shfl_down(s2, off);
    }
    if (lane == 0) { r1[wave] = s1; r2[wave] = s2; }
    __syncthreads();
    if (t < 64) {
        float S1 = (t < 16) ? r1[t] : 0.f;
        float S2 = (t < 16) ? r2[t] : 0.f;
        #pragma unroll
        for (int off = 8; off > 0; off >>= 1) {
            S1 += __shfl_down(S1, off);
            S2 += __shfl_down(S2, off);
        }
        if (t == 0) {
            float mean = S1 * (1.f / (float)HW);
            float var  = (S2 - S1 * mean) * (1.f / (float)(HW - 1));
            var = fmaxf(var, 0.f);
            bc[4] = mean;
            bc[5] = weight[g] / (sqrtf(var) + 1e-5f);
        }
    }
    __syncthreads();
    const float mean = bc[4], wsc = bc[5];
    const float wb = fmaf(-mean, wsc, bias[g]);   // ctx = sim*wsc + wb

    // ---- sweep 3: gated output, non-temporal stores (write-once stream) ----
    #pragma unroll
    for (int k = 0; k < VPT; ++k) {
        const float ur = urow[wave + 16 * k];
        float4 q = v[k];
        vf4 o;
        {
            float f = ur + cw.x, sim = f * q.x;
            float ctx = fmaf(sim, wsc, wb);
            o.x = q.x * __builtin_amdgcn_rcpf(1.f + __expf(-ctx));
        }
        {
            float f = ur + cw.y, sim = f * q.y;
            float ctx = fmaf(sim, wsc, wb);
            o.y = q.y * __builtin_amdgcn_rcpf(1.f + __expf(-ctx));
        }
        {
            float f = ur + cw.z, sim = f * q.z;
            float ctx = fmaf(sim, wsc, wb);
            o.z = q.z * __builtin_amdgcn_rcpf(1.f + __expf(-ctx));
        }
        {
            float f = ur + cw.w, sim = f * q.w;
            float ctx = fmaf(sim, wsc, wb);
            o.w = q.w * __builtin_amdgcn_rcpf(1.f + __expf(-ctx));
        }
        __builtin_nontemporal_store(o, reinterpret_cast<vf4*>(out4 + base4 + t + k * TPB));
    }
}

extern "C" void kernel_launch(void* const* d_in, const int* in_sizes, int n_in,
                              void* d_out, int out_size, void* d_ws, size_t ws_size,
                              hipStream_t stream) {
    const float* x      = (const float*)d_in[0];
    const float* weight = (const float*)d_in[1];
    const float* bias   = (const float*)d_in[2];
    const float* one_   = (const float*)d_in[3];
    const float* zero   = (const float*)d_in[4];
    const float* theta  = (const float*)d_in[5];
    const float* scale  = (const float*)d_in[6];
    float* out = (float*)d_out;

    k_fused<<<BG, TPB, 0, stream>>>((const float4*)x, weight, bias, one_, zero,
                                    theta, scale, (float4*)out);
}